// Round 9
// baseline (47.950 us; speedup 1.0000x reference)
//
#include <hip/hip_runtime.h>
#include <hip/hip_bf16.h>

// Outer_14173392076867 — 3-kernel high-occupancy pipeline v8, MI355X gfx950.
// K1 k_att: per-(n,h) dX -> att MFMA -> att bf16[n][h][i][d] in ws.
//           2048 blocks x 256 thr, ~35 KB LDS -> 4 blocks/CU (16 waves/CU).
// K2 k_fc1: k-split GEMM att[256 x 32768] @ fc1_w^T -> partial[sp][256][64].
//           256 blocks (k-chunk 128); fc1_w staged f32->bf16 LDS once
//           (total w1 read = 8 MB, minimal).
// K3 k_fc2: reduce 256 partials + bias + silu + fc2 -> out[256].

typedef __attribute__((ext_vector_type(8))) short short8;
typedef __attribute__((ext_vector_type(4))) float f32x4;
typedef __attribute__((ext_vector_type(4))) unsigned short u16x4;

#define PADW 88      // 176B rows: 16B-aligned
#define KTOT 32768L

__device__ __forceinline__ unsigned short f2b(float x) {
  union { float f; unsigned int u; } v; v.f = x;
  return (unsigned short)((v.u + 0x7FFFu + ((v.u >> 16) & 1u)) >> 16);
}

// packed f32x2 -> bf16x2 (RNE); ONLY used as a direct scalar dword store
// (v7-proven pattern; do NOT assemble results into vector operands).
__device__ __forceinline__ unsigned int pk_bf16(float a, float b) {
  unsigned int r;
  asm("v_cvt_pk_bf16_f32 %0, %1, %2" : "=v"(r) : "v"(a), "v"(b));
  return r;
}

// ---------------- K1: att[n,h,i,d] ----------------
// grid = 2048 (n*8+h), block = 256 (4 waves). Wave w owns i-rows [16w,16w+16).
__global__ __launch_bounds__(256, 4)
void k_att(const float* __restrict__ X, const float* __restrict__ Wl_g,
           const float* __restrict__ Wr_g, unsigned short* __restrict__ att) {
  __shared__ float xs[3][64];
  __shared__ __align__(16) unsigned short wl[64][PADW];  // [d][j]
  __shared__ __align__(16) unsigned short wr[64][PADW];
  __shared__ __align__(16) unsigned short dx[64][PADW];  // [i][j]

  const int blk  = blockIdx.x;       // n*8 + h
  const int h    = blk & 7;
  const int tid  = threadIdx.x;
  const int lane = tid & 63;
  const int w    = tid >> 6;
  const int c0   = lane & 15;
  const int ks   = lane >> 4;

  if (tid < 192) {
    float v = X[blk * 192 + tid];
    int i = tid / 3, t = tid - i * 3;
    xs[t][i] = v;
  }
  const float* wlg = Wl_g + h * 4096;
  const float* wrg = Wr_g + h * 4096;
  for (int e = tid; e < 4096; e += 256) {
    int j = e >> 6, d = e & 63;
    wl[d][j] = f2b(wlg[e]);
    wr[d][j] = f2b(wrg[e]);
  }
  __syncthreads();

  short8 bl[4][2], br[4][2];
#pragma unroll
  for (int cb = 0; cb < 4; ++cb)
#pragma unroll
    for (int kb = 0; kb < 2; ++kb) {
      const int d = c0 + 16 * cb;
      const int j0 = ks * 8 + 32 * kb;
      bl[cb][kb] = *(const short8*)&wl[d][j0];
      br[cb][kb] = *(const short8*)&wr[d][j0];
    }

  f32x4 acc[4];
#pragma unroll
  for (int cb = 0; cb < 4; ++cb) {
    acc[cb][0] = 0.f; acc[cb][1] = 0.f; acc[cb][2] = 0.f; acc[cb][3] = 0.f;
  }

  const int di  = tid >> 2;
  const int dj0 = (tid & 3) << 4;

  for (int t = 0; t < 3; ++t) {
    const float xi = xs[t][di];
#pragma unroll
    for (int jj = 0; jj < 16; jj += 2) {
      float d0 = xi - xs[t][dj0 + jj];
      float d1 = xi - xs[t][dj0 + jj + 1];
      float s0 = d0 * d0 + 1e-5f;
      float s1 = d1 * d1 + 1e-5f;
      float i0 = __builtin_amdgcn_rsqf(s0);
      float i1 = __builtin_amdgcn_rsqf(s1);
      float e0 = __builtin_amdgcn_exp2f(-1.44269504f * (s0 * i0));
      float e1 = __builtin_amdgcn_exp2f(-1.44269504f * (s1 * i1));
      *(unsigned int*)&dx[di][dj0 + jj] =
          pk_bf16(d0 * i0 * e0, d1 * i1 * e1);
    }
    __syncthreads();

    short8 a0 = *(const short8*)&dx[16 * w + c0][ks * 8];
    short8 a1 = *(const short8*)&dx[16 * w + c0][ks * 8 + 32];
#pragma unroll
    for (int cb = 0; cb < 4; ++cb) {
      f32x4 xl; xl[0]=0.f; xl[1]=0.f; xl[2]=0.f; xl[3]=0.f;
      f32x4 xr; xr[0]=0.f; xr[1]=0.f; xr[2]=0.f; xr[3]=0.f;
      xl = __builtin_amdgcn_mfma_f32_16x16x32_bf16(a0, bl[cb][0], xl, 0, 0, 0);
      xl = __builtin_amdgcn_mfma_f32_16x16x32_bf16(a1, bl[cb][1], xl, 0, 0, 0);
      xr = __builtin_amdgcn_mfma_f32_16x16x32_bf16(a0, br[cb][0], xr, 0, 0, 0);
      xr = __builtin_amdgcn_mfma_f32_16x16x32_bf16(a1, br[cb][1], xr, 0, 0, 0);
      acc[cb] += xl * xr;
    }
    if (t < 2) __syncthreads();      // dx overwrite vs A-reads
  }

  // att[n][h][i][d]: i = 16w + ks*4 + r, d = c0 + 16cb
  unsigned short* ap = att + (long)blk * 4096;
#pragma unroll
  for (int cb = 0; cb < 4; ++cb)
#pragma unroll
    for (int r = 0; r < 4; ++r)
      ap[(16 * w + ks * 4 + r) * 64 + c0 + 16 * cb] = f2b(acc[cb][r]);
}

// ---------------- K2: partial[sp] = att @ w1^T over k-chunk 128 ----------------
// grid = 256 (sp), block = 256 (4 waves). Wave w owns n-rows [64w, 64w+64).
__global__ __launch_bounds__(256, 4)
void k_fc1(const unsigned short* __restrict__ att,
           const float* __restrict__ fc1w, float* __restrict__ partial) {
  __shared__ __align__(16) unsigned short bs[64][136];   // [out][k], pad 8

  const int sp   = blockIdx.x;
  const int tid  = threadIdx.x;
  const int lane = tid & 63;
  const int w    = tid >> 6;
  const int c0   = lane & 15;
  const int ks   = lane >> 4;

  // stage B: w1[64 out][128 k] f32 -> bf16 LDS (each block reads 32 KB once)
#pragma unroll
  for (int r = 0; r < 8; ++r) {
    int e = tid + r * 256;           // e in [0, 2048)
    int out = e >> 5, v = e & 31;
    f32x4 src = *(const f32x4*)(fc1w + (long)out * KTOT + sp * 128 + v * 4);
    u16x4 o;
#pragma unroll
    for (int q = 0; q < 4; ++q) o[q] = f2b(src[q]);
    *(u16x4*)&bs[out][v * 4] = o;
  }
  __syncthreads();

  f32x4 facc[4][4];
#pragma unroll
  for (int mt = 0; mt < 4; ++mt)
#pragma unroll
    for (int cb = 0; cb < 4; ++cb) {
      facc[mt][cb][0] = 0.f; facc[mt][cb][1] = 0.f;
      facc[mt][cb][2] = 0.f; facc[mt][cb][3] = 0.f;
    }

  const unsigned short* abase = att + sp * 128 + ks * 8;
#pragma unroll
  for (int kstep = 0; kstep < 4; ++kstep) {
    short8 a[4];
#pragma unroll
    for (int mt = 0; mt < 4; ++mt) {
      int row = w * 64 + mt * 16 + c0;
      a[mt] = *(const short8*)(abase + (long)row * KTOT + kstep * 32);
    }
#pragma unroll
    for (int cb = 0; cb < 4; ++cb) {
      short8 b = *(const short8*)&bs[c0 + 16 * cb][kstep * 32 + ks * 8];
#pragma unroll
      for (int mt = 0; mt < 4; ++mt)
        facc[mt][cb] = __builtin_amdgcn_mfma_f32_16x16x32_bf16(a[mt], b, facc[mt][cb], 0, 0, 0);
    }
  }

  float* pp = partial + (long)sp * 16384;
#pragma unroll
  for (int mt = 0; mt < 4; ++mt)
#pragma unroll
    for (int cb = 0; cb < 4; ++cb)
#pragma unroll
      for (int r = 0; r < 4; ++r)
        pp[(w * 64 + mt * 16 + ks * 4 + r) * 64 + cb * 16 + c0] = facc[mt][cb][r];
}

// ---------------- K3: reduce 256 partials + bias + silu + fc2 ----------------
// grid = 256 (n), block = 256: group g sums sp in [64g, 64g+64).
__global__ __launch_bounds__(256)
void k_fc2(const float* __restrict__ partial, const float* __restrict__ fc1_b,
           const float* __restrict__ fc2_w, const float* __restrict__ fc2_b,
           float* __restrict__ out) {
  __shared__ float red[4][64];
  const int n = blockIdx.x;
  const int tid = threadIdx.x;
  const int k = tid & 63;
  const int g = tid >> 6;
  float s = 0.f;
#pragma unroll 8
  for (int sp = g * 64; sp < g * 64 + 64; ++sp)
    s += partial[(long)sp * 16384 + n * 64 + k];
  red[g][k] = s;
  __syncthreads();
  if (tid < 64) {
    float v = red[0][k] + red[1][k] + red[2][k] + red[3][k] + fc1_b[k];
    float gg = v / (1.f + __expf(-v));   // silu
    float z = gg * fc2_w[k];
#pragma unroll
    for (int off = 32; off > 0; off >>= 1)
      z += __shfl_xor(z, off, 64);
    if (k == 0) out[n] = z + fc2_b[0];
  }
}

extern "C" void kernel_launch(void* const* d_in, const int* in_sizes, int n_in,
                              void* d_out, int out_size, void* d_ws, size_t ws_size,
                              hipStream_t stream) {
  const float* X    = (const float*)d_in[0];
  const float* Wl   = (const float*)d_in[1];
  const float* Wr   = (const float*)d_in[2];
  const float* fc1w = (const float*)d_in[3];
  const float* fc1b = (const float*)d_in[4];
  const float* fc2w = (const float*)d_in[5];
  const float* fc2b = (const float*)d_in[6];
  float* out = (float*)d_out;

  char* ws = (char*)d_ws;
  unsigned short* att     = (unsigned short*)(ws);             // 16,777,216 B
  float*          partial = (float*)(ws + 16777216);           // 16,777,216 B

  hipLaunchKernelGGL(k_att, dim3(2048), dim3(256), 0, stream, X, Wl, Wr, att);
  hipLaunchKernelGGL(k_fc1, dim3(256), dim3(256), 0, stream, att, fc1w, partial);
  hipLaunchKernelGGL(k_fc2, dim3(256), dim3(256), 0, stream, partial, fc1b, fc2w, fc2b, out);
}

// Round 10
// 32.781 us; speedup vs baseline: 1.4627x; 1.4627x over previous
//
#include <hip/hip_runtime.h>
#include <hip/hip_bf16.h>

// Outer_14173392076867 — 2-kernel pipeline v9, MI355X gfx950.
// K1: fused per-(iq,h,ng16): dX -> att (LDS, 16 n x 1024 m) -> fc1 partial,
//     i-QUARTER per block: LDS 78 KB -> 2 blocks/CU (4 waves/SIMD).
// K2: reduce 32 partials + bias + silu + fc2 -> out[256]

typedef __attribute__((ext_vector_type(8))) short short8;
typedef __attribute__((ext_vector_type(4))) float f32x4;

#define PADW 72      // LDS row pad (ushorts): 144B rows, 16B aligned
#define PADM 1032    // att row: 1024 + 8 ushorts -> 2064B rows
#define KTOT 32768L

__device__ __forceinline__ unsigned short f2b(float x) {
  union { float f; unsigned int u; } v; v.f = x;
  return (unsigned short)((v.u + 0x7FFFu + ((v.u >> 16) & 1u)) >> 16);
}

// packed f32x2 -> bf16x2 (RNE), single v_cvt_pk_bf16_f32; used only as a
// direct dword store (v7-proven pattern).
__device__ __forceinline__ unsigned int pk_bf16(float a, float b) {
  unsigned int r;
  asm("v_cvt_pk_bf16_f32 %0, %1, %2" : "=v"(r) : "v"(a), "v"(b));
  return r;
}

// ---------------- K1: fused dX -> att (LDS) -> fc1 partial ----------------
// grid = 512: iq = blk&3 (i-quarter), h = (blk>>2)&7, ng = blk>>5 (16 n's).
// block = 512 (8 waves). Phase A: 8 double-q iterations (2 q in flight);
// wave w: qsub = w&1, dblk = w>>1 (16-wide d block). Per-q tile [16i x 64d].
// Phase B: wave w owns m-chunk 128 of this block's 1024; 16-row A-frags.
__global__ __launch_bounds__(512, 4)
void k_fused(const float* __restrict__ X, const float* __restrict__ Wl_g,
             const float* __restrict__ Wr_g,
             const float* __restrict__ fc1w,
             float* __restrict__ partial) {
  __shared__ float xs[16][3][64];                              // 12288 B
  __shared__ __align__(16) union {
    struct {
      unsigned short wl[64][PADW];                             //  9216 B
      unsigned short wr[64][PADW];                             //  9216 B
      unsigned short dxs[2][3][16][PADW];                      // 13824 B
    } a;
    float red[8][16][64];                                      // 32768 B
  } u;                                                         // 32768 B
  __shared__ __align__(16) unsigned short att_s[16][PADM];     // 33024 B => 78080 B

  const int blk  = blockIdx.x;
  const int iq   = blk & 3;
  const int h    = (blk >> 2) & 7;
  const int ng   = blk >> 5;
  const int tid  = threadIdx.x;
  const int lane = tid & 63;
  const int w    = tid >> 6;
  const int c0   = lane & 15;
  const int ks   = lane >> 4;
  const int qsub = w & 1;
  const int dblk = w >> 1;

  // ---- W slices (per h): coalesced f32 read, transposed bf16 store [d][j]
  const float* wlg = Wl_g + h * 4096;
  const float* wrg = Wr_g + h * 4096;
#pragma unroll
  for (int r = 0; r < 8; ++r) {
    int e = tid + r * 512;
    int j = e >> 6, d = e & 63;
    u.a.wl[d][j] = f2b(wlg[e]);
    u.a.wr[d][j] = f2b(wrg[e]);
  }
  // ---- X for 16 n: [q][t][i] (3072 floats, coalesced)
  {
    const long xbase = ((long)(ng * 16) * 8 + h) * 192;
#pragma unroll
    for (int r = 0; r < 6; ++r) {
      int e = tid + r * 512;
      int q = e / 192;
      int rem = e - q * 192;
      int i = rem / 3;
      int t = rem - i * 3;
      xs[q][t][i] = X[xbase + (long)q * 1536 + rem];
    }
  }
  __syncthreads();

  // ---- B fragments for the att GEMM (this wave's 16-wide d block)
  short8 bl[2], br[2];
#pragma unroll
  for (int kb = 0; kb < 2; ++kb) {
    const int d = dblk * 16 + c0;
    const int j0 = ks * 8 + 32 * kb;
    bl[kb] = *(const short8*)&u.a.wl[d][j0];
    br[kb] = *(const short8*)&u.a.wr[d][j0];
  }

  const int dq = tid >> 8;           // dX sub-buffer this thread fills (0/1)
  const int il = (tid >> 4) & 15;    // dX row (local, 0..15)
  const int j4 = (tid & 15) << 2;    // 4-col chunk

  for (int it = 0; it < 8; ++it) {
    const int qd = it * 2 + dq;
    if (it) __syncthreads();
    // dX[i = iq*16+il][j], 3 t's, 4 j's per thread
#pragma unroll
    for (int t = 0; t < 3; ++t) {
      const float xi = xs[qd][t][iq * 16 + il];
      float d0 = xi - xs[qd][t][j4];
      float d1 = xi - xs[qd][t][j4 + 1];
      float d2 = xi - xs[qd][t][j4 + 2];
      float d3 = xi - xs[qd][t][j4 + 3];
      float s0 = d0 * d0 + 1e-5f, s1 = d1 * d1 + 1e-5f;
      float s2 = d2 * d2 + 1e-5f, s3 = d3 * d3 + 1e-5f;
      float i0 = __builtin_amdgcn_rsqf(s0), i1 = __builtin_amdgcn_rsqf(s1);
      float i2 = __builtin_amdgcn_rsqf(s2), i3 = __builtin_amdgcn_rsqf(s3);
      float e0 = __builtin_amdgcn_exp2f(-1.44269504f * (s0 * i0));
      float e1 = __builtin_amdgcn_exp2f(-1.44269504f * (s1 * i1));
      float e2 = __builtin_amdgcn_exp2f(-1.44269504f * (s2 * i2));
      float e3 = __builtin_amdgcn_exp2f(-1.44269504f * (s3 * i3));
      *(unsigned int*)&u.a.dxs[dq][t][il][j4] =
          pk_bf16(d0 * i0 * e0, d1 * i1 * e1);
      *(unsigned int*)&u.a.dxs[dq][t][il][j4 + 2] =
          pk_bf16(d2 * i2 * e2, d3 * i3 * e3);
    }
    __syncthreads();

    // att tile for q = it*2 + qsub: wave computes [16 i x 16 d], K=64 over j
    const int q = it * 2 + qsub;
    f32x4 acc;
    acc[0] = 0.f; acc[1] = 0.f; acc[2] = 0.f; acc[3] = 0.f;
#pragma unroll
    for (int t = 0; t < 3; ++t) {
      short8 a0 = *(const short8*)&u.a.dxs[qsub][t][c0][ks * 8];
      short8 a1 = *(const short8*)&u.a.dxs[qsub][t][c0][ks * 8 + 32];
      f32x4 xl; xl[0]=0.f; xl[1]=0.f; xl[2]=0.f; xl[3]=0.f;
      f32x4 xr; xr[0]=0.f; xr[1]=0.f; xr[2]=0.f; xr[3]=0.f;
      xl = __builtin_amdgcn_mfma_f32_16x16x32_bf16(a0, bl[0], xl, 0, 0, 0);
      xl = __builtin_amdgcn_mfma_f32_16x16x32_bf16(a1, bl[1], xl, 0, 0, 0);
      xr = __builtin_amdgcn_mfma_f32_16x16x32_bf16(a0, br[0], xr, 0, 0, 0);
      xr = __builtin_amdgcn_mfma_f32_16x16x32_bf16(a1, br[1], xr, 0, 0, 0);
      acc += xl * xr;
    }
    // store: m-local = i_local*64 + d = (ks*4+r)*64 + dblk*16 + c0
#pragma unroll
    for (int r = 0; r < 4; ++r)
      att_s[q][(ks * 4 + r) * 64 + dblk * 16 + c0] = f2b(acc[r]);
  }
  __syncthreads();

  // ---- Phase B: fc1 partial, C[16n x 64k], wave w owns m-chunk 128.
  // B-frags streamed from fc1w (f32), f2b-converted (v7-proven union pattern).
  f32x4 facc[4];
#pragma unroll
  for (int cb = 0; cb < 4; ++cb) {
    facc[cb][0] = 0.f; facc[cb][1] = 0.f; facc[cb][2] = 0.f; facc[cb][3] = 0.f;
  }
  const float* bpf =
      fc1w + (long)c0 * KTOT + h * 4096 + iq * 1024 + w * 128 + ks * 8;
  const unsigned short* ap = &att_s[0][0] + c0 * PADM + w * 128 + ks * 8;
#pragma unroll
  for (int s = 0; s < 4; ++s) {
    short8 a = *(const short8*)(ap + s * 32);
#pragma unroll
    for (int cb = 0; cb < 4; ++cb) {
      const float* src = bpf + (long)cb * 16 * KTOT + s * 32;
      f32x4 v0 = *(const f32x4*)(src);
      f32x4 v1 = *(const f32x4*)(src + 4);
      union { unsigned short us[8]; short8 s8; } pw;
      pw.us[0] = f2b(v0[0]);
      pw.us[1] = f2b(v0[1]);
      pw.us[2] = f2b(v0[2]);
      pw.us[3] = f2b(v0[3]);
      pw.us[4] = f2b(v1[0]);
      pw.us[5] = f2b(v1[1]);
      pw.us[6] = f2b(v1[2]);
      pw.us[7] = f2b(v1[3]);
      facc[cb] = __builtin_amdgcn_mfma_f32_16x16x32_bf16(a, pw.s8, facc[cb], 0, 0, 0);
    }
  }
  __syncthreads();                   // att_s/u.a reads done; u.red reuse
#pragma unroll
  for (int cb = 0; cb < 4; ++cb)
#pragma unroll
    for (int r = 0; r < 4; ++r)
      u.red[w][ks * 4 + r][c0 + 16 * cb] = facc[cb][r];
  __syncthreads();
#pragma unroll
  for (int rep = 0; rep < 2; ++rep) {
    int e = tid + rep * 512;
    int nl = e >> 6, k = e & 63;
    float s = 0.f;
#pragma unroll
    for (int ww = 0; ww < 8; ++ww) s += u.red[ww][nl][k];
    partial[(((long)h * 4 + iq) * 256 + ng * 16 + nl) * 64 + k] = s;
  }
}

// ---------------- K2: reduce 32 partials + bias + silu + fc2 ----------------
__global__ __launch_bounds__(256)
void k_fc2(const float* __restrict__ partial, const float* __restrict__ fc1_b,
           const float* __restrict__ fc2_w, const float* __restrict__ fc2_b,
           float* __restrict__ out) {
  const int tid = threadIdx.x;
  const int n = blockIdx.x * 4 + (tid >> 6);
  const int k = tid & 63;
  float s = fc1_b[k];
#pragma unroll
  for (int sp = 0; sp < 32; ++sp)
    s += partial[((long)sp * 256 + n) * 64 + k];
  float g = s / (1.f + __expf(-s));   // silu
  float v = g * fc2_w[k];
#pragma unroll
  for (int off = 32; off > 0; off >>= 1)
    v += __shfl_xor(v, off, 64);
  if (k == 0) out[n] = v + fc2_b[0];
}

extern "C" void kernel_launch(void* const* d_in, const int* in_sizes, int n_in,
                              void* d_out, int out_size, void* d_ws, size_t ws_size,
                              hipStream_t stream) {
  const float* X    = (const float*)d_in[0];
  const float* Wl   = (const float*)d_in[1];
  const float* Wr   = (const float*)d_in[2];
  const float* fc1w = (const float*)d_in[3];
  const float* fc1b = (const float*)d_in[4];
  const float* fc2w = (const float*)d_in[5];
  const float* fc2b = (const float*)d_in[6];
  float* out = (float*)d_out;

  float* partial = (float*)d_ws;                               // 2,097,152 B

  hipLaunchKernelGGL(k_fused, dim3(512), dim3(512), 0, stream, X, Wl, Wr, fc1w, partial);
  hipLaunchKernelGGL(k_fc2,   dim3(64), dim3(256), 0, stream, partial, fc1b, fc2w, fc2b, out);
}

// Round 11
// 32.767 us; speedup vs baseline: 1.4634x; 1.0004x over previous
//
#include <hip/hip_runtime.h>
#include <hip/hip_bf16.h>

// Outer_14173392076867 — 2-kernel pipeline v10, MI355X gfx950.
// v9 + XCD-locality swizzle: all 16 ng-sharers of one (h,iq) fc1_w slice map
// to the same XCD (blk%8 == slice%8), making the 256KB slice L2-resident
// (per-XCD working set 1 MB << 4 MB L2). Everything else identical to v9.
// K1: fused per-(iq,h,ng16): dX -> att (LDS) -> fc1 partial, 2 blocks/CU.
// K2: reduce 32 partials + bias + silu + fc2 -> out[256]

typedef __attribute__((ext_vector_type(8))) short short8;
typedef __attribute__((ext_vector_type(4))) float f32x4;

#define PADW 72      // LDS row pad (ushorts): 144B rows, 16B aligned
#define PADM 1032    // att row: 1024 + 8 ushorts -> 2064B rows
#define KTOT 32768L

__device__ __forceinline__ unsigned short f2b(float x) {
  union { float f; unsigned int u; } v; v.f = x;
  return (unsigned short)((v.u + 0x7FFFu + ((v.u >> 16) & 1u)) >> 16);
}

// packed f32x2 -> bf16x2 (RNE), single v_cvt_pk_bf16_f32; used only as a
// direct dword store (v7-proven pattern).
__device__ __forceinline__ unsigned int pk_bf16(float a, float b) {
  unsigned int r;
  asm("v_cvt_pk_bf16_f32 %0, %1, %2" : "=v"(r) : "v"(a), "v"(b));
  return r;
}

// ---------------- K1: fused dX -> att (LDS) -> fc1 partial ----------------
// grid = 512. XCD swizzle: sl = ((blk>>7)<<3)|(blk&7) in 0..31 -> iq = sl&3,
// h = sl>>2; ng = (blk>>3)&15. Sharers of a slice co-locate per XCD.
// block = 512 (8 waves). Phase A: 8 double-q iterations (2 q in flight);
// wave w: qsub = w&1, dblk = w>>1 (16-wide d block). Per-q tile [16i x 64d].
// Phase B: wave w owns m-chunk 128 of this block's 1024; 16-row A-frags.
__global__ __launch_bounds__(512, 4)
void k_fused(const float* __restrict__ X, const float* __restrict__ Wl_g,
             const float* __restrict__ Wr_g,
             const float* __restrict__ fc1w,
             float* __restrict__ partial) {
  __shared__ float xs[16][3][64];                              // 12288 B
  __shared__ __align__(16) union {
    struct {
      unsigned short wl[64][PADW];                             //  9216 B
      unsigned short wr[64][PADW];                             //  9216 B
      unsigned short dxs[2][3][16][PADW];                      // 13824 B
    } a;
    float red[8][16][64];                                      // 32768 B
  } u;                                                         // 32768 B
  __shared__ __align__(16) unsigned short att_s[16][PADM];     // 33024 B => 78080 B

  const int blk  = blockIdx.x;
  const int sl   = ((blk >> 7) << 3) | (blk & 7);  // slice (h,iq) in 0..31
  const int iq   = sl & 3;
  const int h    = sl >> 2;
  const int ng   = (blk >> 3) & 15;
  const int tid  = threadIdx.x;
  const int lane = tid & 63;
  const int w    = tid >> 6;
  const int c0   = lane & 15;
  const int ks   = lane >> 4;
  const int qsub = w & 1;
  const int dblk = w >> 1;

  // ---- W slices (per h): coalesced f32 read, transposed bf16 store [d][j]
  const float* wlg = Wl_g + h * 4096;
  const float* wrg = Wr_g + h * 4096;
#pragma unroll
  for (int r = 0; r < 8; ++r) {
    int e = tid + r * 512;
    int j = e >> 6, d = e & 63;
    u.a.wl[d][j] = f2b(wlg[e]);
    u.a.wr[d][j] = f2b(wrg[e]);
  }
  // ---- X for 16 n: [q][t][i] (3072 floats, coalesced)
  {
    const long xbase = ((long)(ng * 16) * 8 + h) * 192;
#pragma unroll
    for (int r = 0; r < 6; ++r) {
      int e = tid + r * 512;
      int q = e / 192;
      int rem = e - q * 192;
      int i = rem / 3;
      int t = rem - i * 3;
      xs[q][t][i] = X[xbase + (long)q * 1536 + rem];
    }
  }
  __syncthreads();

  // ---- B fragments for the att GEMM (this wave's 16-wide d block)
  short8 bl[2], br[2];
#pragma unroll
  for (int kb = 0; kb < 2; ++kb) {
    const int d = dblk * 16 + c0;
    const int j0 = ks * 8 + 32 * kb;
    bl[kb] = *(const short8*)&u.a.wl[d][j0];
    br[kb] = *(const short8*)&u.a.wr[d][j0];
  }

  const int dq = tid >> 8;           // dX sub-buffer this thread fills (0/1)
  const int il = (tid >> 4) & 15;    // dX row (local, 0..15)
  const int j4 = (tid & 15) << 2;    // 4-col chunk

  for (int it = 0; it < 8; ++it) {
    const int qd = it * 2 + dq;
    if (it) __syncthreads();
    // dX[i = iq*16+il][j], 3 t's, 4 j's per thread
#pragma unroll
    for (int t = 0; t < 3; ++t) {
      const float xi = xs[qd][t][iq * 16 + il];
      float d0 = xi - xs[qd][t][j4];
      float d1 = xi - xs[qd][t][j4 + 1];
      float d2 = xi - xs[qd][t][j4 + 2];
      float d3 = xi - xs[qd][t][j4 + 3];
      float s0 = d0 * d0 + 1e-5f, s1 = d1 * d1 + 1e-5f;
      float s2 = d2 * d2 + 1e-5f, s3 = d3 * d3 + 1e-5f;
      float i0 = __builtin_amdgcn_rsqf(s0), i1 = __builtin_amdgcn_rsqf(s1);
      float i2 = __builtin_amdgcn_rsqf(s2), i3 = __builtin_amdgcn_rsqf(s3);
      float e0 = __builtin_amdgcn_exp2f(-1.44269504f * (s0 * i0));
      float e1 = __builtin_amdgcn_exp2f(-1.44269504f * (s1 * i1));
      float e2 = __builtin_amdgcn_exp2f(-1.44269504f * (s2 * i2));
      float e3 = __builtin_amdgcn_exp2f(-1.44269504f * (s3 * i3));
      *(unsigned int*)&u.a.dxs[dq][t][il][j4] =
          pk_bf16(d0 * i0 * e0, d1 * i1 * e1);
      *(unsigned int*)&u.a.dxs[dq][t][il][j4 + 2] =
          pk_bf16(d2 * i2 * e2, d3 * i3 * e3);
    }
    __syncthreads();

    // att tile for q = it*2 + qsub: wave computes [16 i x 16 d], K=64 over j
    const int q = it * 2 + qsub;
    f32x4 acc;
    acc[0] = 0.f; acc[1] = 0.f; acc[2] = 0.f; acc[3] = 0.f;
#pragma unroll
    for (int t = 0; t < 3; ++t) {
      short8 a0 = *(const short8*)&u.a.dxs[qsub][t][c0][ks * 8];
      short8 a1 = *(const short8*)&u.a.dxs[qsub][t][c0][ks * 8 + 32];
      f32x4 xl; xl[0]=0.f; xl[1]=0.f; xl[2]=0.f; xl[3]=0.f;
      f32x4 xr; xr[0]=0.f; xr[1]=0.f; xr[2]=0.f; xr[3]=0.f;
      xl = __builtin_amdgcn_mfma_f32_16x16x32_bf16(a0, bl[0], xl, 0, 0, 0);
      xl = __builtin_amdgcn_mfma_f32_16x16x32_bf16(a1, bl[1], xl, 0, 0, 0);
      xr = __builtin_amdgcn_mfma_f32_16x16x32_bf16(a0, br[0], xr, 0, 0, 0);
      xr = __builtin_amdgcn_mfma_f32_16x16x32_bf16(a1, br[1], xr, 0, 0, 0);
      acc += xl * xr;
    }
    // store: m-local = i_local*64 + d = (ks*4+r)*64 + dblk*16 + c0
#pragma unroll
    for (int r = 0; r < 4; ++r)
      att_s[q][(ks * 4 + r) * 64 + dblk * 16 + c0] = f2b(acc[r]);
  }
  __syncthreads();

  // ---- Phase B: fc1 partial, C[16n x 64k], wave w owns m-chunk 128.
  // B-frags streamed from fc1w (f32, L2-resident slice), f2b-converted.
  f32x4 facc[4];
#pragma unroll
  for (int cb = 0; cb < 4; ++cb) {
    facc[cb][0] = 0.f; facc[cb][1] = 0.f; facc[cb][2] = 0.f; facc[cb][3] = 0.f;
  }
  const float* bpf =
      fc1w + (long)c0 * KTOT + h * 4096 + iq * 1024 + w * 128 + ks * 8;
  const unsigned short* ap = &att_s[0][0] + c0 * PADM + w * 128 + ks * 8;
#pragma unroll
  for (int s = 0; s < 4; ++s) {
    short8 a = *(const short8*)(ap + s * 32);
#pragma unroll
    for (int cb = 0; cb < 4; ++cb) {
      const float* src = bpf + (long)cb * 16 * KTOT + s * 32;
      f32x4 v0 = *(const f32x4*)(src);
      f32x4 v1 = *(const f32x4*)(src + 4);
      union { unsigned short us[8]; short8 s8; } pw;
      pw.us[0] = f2b(v0[0]);
      pw.us[1] = f2b(v0[1]);
      pw.us[2] = f2b(v0[2]);
      pw.us[3] = f2b(v0[3]);
      pw.us[4] = f2b(v1[0]);
      pw.us[5] = f2b(v1[1]);
      pw.us[6] = f2b(v1[2]);
      pw.us[7] = f2b(v1[3]);
      facc[cb] = __builtin_amdgcn_mfma_f32_16x16x32_bf16(a, pw.s8, facc[cb], 0, 0, 0);
    }
  }
  __syncthreads();                   // att_s/u.a reads done; u.red reuse
#pragma unroll
  for (int cb = 0; cb < 4; ++cb)
#pragma unroll
    for (int r = 0; r < 4; ++r)
      u.red[w][ks * 4 + r][c0 + 16 * cb] = facc[cb][r];
  __syncthreads();
#pragma unroll
  for (int rep = 0; rep < 2; ++rep) {
    int e = tid + rep * 512;
    int nl = e >> 6, k = e & 63;
    float s = 0.f;
#pragma unroll
    for (int ww = 0; ww < 8; ++ww) s += u.red[ww][nl][k];
    partial[(((long)h * 4 + iq) * 256 + ng * 16 + nl) * 64 + k] = s;
  }
}

// ---------------- K2: reduce 32 partials + bias + silu + fc2 ----------------
__global__ __launch_bounds__(256)
void k_fc2(const float* __restrict__ partial, const float* __restrict__ fc1_b,
           const float* __restrict__ fc2_w, const float* __restrict__ fc2_b,
           float* __restrict__ out) {
  const int tid = threadIdx.x;
  const int n = blockIdx.x * 4 + (tid >> 6);
  const int k = tid & 63;
  float s = fc1_b[k];
#pragma unroll
  for (int sp = 0; sp < 32; ++sp)
    s += partial[((long)sp * 256 + n) * 64 + k];
  float g = s / (1.f + __expf(-s));   // silu
  float v = g * fc2_w[k];
#pragma unroll
  for (int off = 32; off > 0; off >>= 1)
    v += __shfl_xor(v, off, 64);
  if (k == 0) out[n] = v + fc2_b[0];
}

extern "C" void kernel_launch(void* const* d_in, const int* in_sizes, int n_in,
                              void* d_out, int out_size, void* d_ws, size_t ws_size,
                              hipStream_t stream) {
  const float* X    = (const float*)d_in[0];
  const float* Wl   = (const float*)d_in[1];
  const float* Wr   = (const float*)d_in[2];
  const float* fc1w = (const float*)d_in[3];
  const float* fc1b = (const float*)d_in[4];
  const float* fc2w = (const float*)d_in[5];
  const float* fc2b = (const float*)d_in[6];
  float* out = (float*)d_out;

  float* partial = (float*)d_ws;                               // 2,097,152 B

  hipLaunchKernelGGL(k_fused, dim3(512), dim3(512), 0, stream, X, Wl, Wr, fc1w, partial);
  hipLaunchKernelGGL(k_fc2,   dim3(64), dim3(256), 0, stream, partial, fc1b, fc2w, fc2b, out);
}